// Round 6
// baseline (191.286 us; speedup 1.0000x reference)
//
#include <hip/hip_runtime.h>

// GAE reverse scan: adv[t] = delta[t] + (gamma*lambda)*adv[t+1]
// delta[t] = reward[t] + gamma*value[t+1] - value[t]
//
// R6: 3-pass, L=8, with a MEMORY-CLOBBER load fence instead of per-value pins.
// R5 post-mortem: per-float4 asm pins were legally interleaved with the loads
// (pin(v0) only depends on v0), so the compiler kept the serialized
// load->wait->use schedule (VGPR=40, ~3 loads in flight, ~3 TB/s wall).
// A single asm volatile("" ::: "memory") AFTER the batch is different: loads
// cannot sink below a memory clobber, so all 2L+1 loads must issue first.
// The register file becomes the prefetch buffer (VGPR ~85 at L=8).
// Loads are issued in reverse consumption order so the first waitcnt drains
// the fewest outstanding loads.
//   K1 gae_sum  : S_c = sum_k COEF^k * delta[8c+k]      (reads 131 MB, writes 8 MB)
//   K2 gae_carry: S[c] <- sum_{j>c} CL^(j-c-1) S[j]     (in place, 64 blocks)
//   K3 gae_out  : recompute local scan seeded with carry, write out ONCE (nt).

constexpr int T_ = 1024;
constexpr int B_ = 16384;
constexpr float GAMMA = 0.99f;
constexpr float COEF  = (float)(0.99 * 0.97);

__host__ __device__ constexpr float pow_coef(int n) {
    float p = 1.0f;
    for (int i = 0; i < n; ++i) p *= COEF;
    return p;
}

typedef float f32x4 __attribute__((ext_vector_type(4)));

static __device__ __forceinline__ void store_nt(float* p, float4 v) {
    f32x4 nv = {v.x, v.y, v.z, v.w};
    __builtin_nontemporal_store(nv, (f32x4*)p);
}

// Compiler-level full memory fence: no load may sink below this point.
#define LOAD_FENCE() __asm__ volatile("" ::: "memory")

// ---------------- K1: weighted chunk sums only ----------------
template<int L>
__global__ __launch_bounds__(256) void gae_sum(
    const float* __restrict__ value,   // (T+1, B)
    const float* __restrict__ reward,  // (T, B)
    float* __restrict__ S)             // (C, B)
{
    const int c4    = blockIdx.x * 256 + threadIdx.x;
    const int chunk = blockIdx.y;
    const size_t b  = (size_t)c4 * 4;
    const int t0    = chunk * L;

    // Issue ALL loads, reverse consumption order (scan consumes i=L-1 first).
    float4 v[L + 1];
    float4 r[L];
    #pragma unroll
    for (int i = L; i >= 0; --i)
        v[i] = *(const float4*)(value + (size_t)(t0 + i) * B_ + b);
    #pragma unroll
    for (int i = L - 1; i >= 0; --i)
        r[i] = *(const float4*)(reward + (size_t)(t0 + i) * B_ + b);
    LOAD_FENCE();   // all 2L+1 loads in flight before the scan consumes any

    float4 s = make_float4(0.f, 0.f, 0.f, 0.f);
    #pragma unroll
    for (int i = L - 1; i >= 0; --i) {
        s.x = (r[i].x + GAMMA * v[i + 1].x - v[i].x) + COEF * s.x;
        s.y = (r[i].y + GAMMA * v[i + 1].y - v[i].y) + COEF * s.y;
        s.z = (r[i].z + GAMMA * v[i + 1].z - v[i].z) + COEF * s.z;
        s.w = (r[i].w + GAMMA * v[i + 1].w - v[i].w) + COEF * s.w;
    }
    *(float4*)(S + (size_t)chunk * B_ + b) = s;
}

// ---------------- K2: in-place carry scan, one thread per scalar column ----
template<int C>
__global__ __launch_bounds__(256) void gae_carry(float* __restrict__ S)
{
    constexpr float CL = pow_coef(T_ / C);   // COEF^L
    const int col = blockIdx.x * 256 + threadIdx.x;   // 0..B-1

    float s[C];
    #pragma unroll
    for (int j = C - 1; j >= 0; --j)
        s[j] = S[(size_t)j * B_ + col];
    LOAD_FENCE();   // all C loads in flight before the serial chain starts

    float run = 0.f;
    #pragma unroll
    for (int j = C - 1; j >= 0; --j) {
        S[(size_t)j * B_ + col] = run;                // carry entering chunk j
        run = s[j] + CL * run;
    }
}

// ---------------- K3: recompute local scan seeded with carry --------------
template<int L>
__global__ __launch_bounds__(256) void gae_out(
    const float* __restrict__ value,   // (T+1, B)  L3-hot from K1
    const float* __restrict__ reward,  // (T, B)    L3-hot from K1
    const float* __restrict__ S,       // (C, B)    now holds carries
    float* __restrict__ out)           // (T, B)    written once, nontemporal
{
    const int c4    = blockIdx.x * 256 + threadIdx.x;
    const int chunk = blockIdx.y;
    const size_t b  = (size_t)c4 * 4;
    const int t0    = chunk * L;

    // carry heads the dependency chain -> load it FIRST, then the batch.
    float4 carry = *(const float4*)(S + (size_t)chunk * B_ + b);
    float4 v[L + 1];
    float4 r[L];
    #pragma unroll
    for (int i = L; i >= 0; --i)
        v[i] = *(const float4*)(value + (size_t)(t0 + i) * B_ + b);
    #pragma unroll
    for (int i = L - 1; i >= 0; --i)
        r[i] = *(const float4*)(reward + (size_t)(t0 + i) * B_ + b);
    LOAD_FENCE();

    float4 a = carry;
    #pragma unroll
    for (int i = L - 1; i >= 0; --i) {
        a.x = (r[i].x + GAMMA * v[i + 1].x - v[i].x) + COEF * a.x;
        a.y = (r[i].y + GAMMA * v[i + 1].y - v[i].y) + COEF * a.y;
        a.z = (r[i].z + GAMMA * v[i + 1].z - v[i].z) + COEF * a.z;
        a.w = (r[i].w + GAMMA * v[i + 1].w - v[i].w) + COEF * a.w;
        store_nt(out + (size_t)(t0 + i) * B_ + b, a);
    }
}

extern "C" void kernel_launch(void* const* d_in, const int* in_sizes, int n_in,
                              void* d_out, int out_size, void* d_ws, size_t ws_size,
                              hipStream_t stream) {
    const float* value  = (const float*)d_in[0];   // (T+1, B)
    const float* reward = (const float*)d_in[1];   // (T, B)
    float* out = (float*)d_out;
    float* S   = (float*)d_ws;

    dim3 block(256);
    dim3 gridC(B_ / 256);                           // 64 blocks, scalar columns

    if (ws_size >= (size_t)(T_ / 8) * B_ * sizeof(float)) {
        // L=8: 2048 blocks for the streaming kernels.
        dim3 grid(B_ / 4 / 256, T_ / 8);            // (16, 128)
        gae_sum<8>  <<<grid,  block, 0, stream>>>(value, reward, S);
        gae_carry<T_/8><<<gridC, block, 0, stream>>>(S);
        gae_out<8>  <<<grid,  block, 0, stream>>>(value, reward, S, out);
    } else {
        dim3 grid(B_ / 4 / 256, T_ / 16);           // (16, 64)
        gae_sum<16> <<<grid,  block, 0, stream>>>(value, reward, S);
        gae_carry<T_/16><<<gridC, block, 0, stream>>>(S);
        gae_out<16> <<<grid,  block, 0, stream>>>(value, reward, S, out);
    }
}

// Round 7
// 189.533 us; speedup vs baseline: 1.0093x; 1.0093x over previous
//
#include <hip/hip_runtime.h>

// GAE reverse scan: adv[t] = delta[t] + (gamma*lambda)*adv[t+1]
// delta[t] = reward[t] + gamma*value[t+1] - value[t]
//
// R7: K1 uses global_load_lds DMA staging (direct-to-LDS, no VGPR round-trip).
// R4-R6 post-mortems: compiler refuses to materialize a register load batch
// (pins interleaved; "memory" clobber defeated by hoisting the register-only
// FMA consumers above it -> VGPR=32, ~3 loads in flight, 2.9 TB/s read wall
// invariant across L, occupancy, pins, fences). global_load_lds is a
// side-effecting intrinsic the compiler cannot fold: 17 DMAs/wave in flight,
// zero VGPR cost. Wave-PRIVATE staging (wave w stages segment w of each row,
// reads only its own segment) -> no __syncthreads, just vmcnt(0).
//   K1 gae_sum_dma : S_c = sum_k COEF^k * delta[8c+k]   (reads 131 MB via DMA)
//   K2 gae_carry   : S[c] <- sum_{j>c} CL^(j-c-1) S[j]  (in place, 64 blocks)
//   K3 gae_out     : recompute local scan seeded w/ carry, write out ONCE (nt).

constexpr int T_ = 1024;
constexpr int B_ = 16384;
constexpr float GAMMA = 0.99f;
constexpr float COEF  = (float)(0.99 * 0.97);

__host__ __device__ constexpr float pow_coef(int n) {
    float p = 1.0f;
    for (int i = 0; i < n; ++i) p *= COEF;
    return p;
}

typedef float f32x4 __attribute__((ext_vector_type(4)));

static __device__ __forceinline__ void store_nt(float* p, float4 v) {
    f32x4 nv = {v.x, v.y, v.z, v.w};
    __builtin_nontemporal_store(nv, (f32x4*)p);
}

#define LOAD_FENCE() __asm__ volatile("" ::: "memory")

// Async global->LDS DMA: 16 B/lane, wave-uniform LDS base + lane*16 dest.
static __device__ __forceinline__ void dma16(const float* g, float* l) {
    __builtin_amdgcn_global_load_lds(
        (const __attribute__((address_space(1))) void*)g,
        (__attribute__((address_space(3))) void*)l, 16, 0, 0);
}

// ---------------- K1: weighted chunk sums, DMA-staged ----------------
template<int L>
__global__ __launch_bounds__(256) void gae_sum_dma(
    const float* __restrict__ value,   // (T+1, B)
    const float* __restrict__ reward,  // (T, B)
    float* __restrict__ S)             // (C, B)
{
    constexpr int ROWS = 2 * L + 1;            // L+1 value rows + L reward rows
    __shared__ float lds[ROWS * 1024];         // 1024 floats (4 KB) per row

    const int tid   = threadIdx.x;
    const int wid   = tid >> 6;                // wave id 0..3
    const int chunk = blockIdx.y;
    const int t0    = chunk * L;
    const size_t col0 = (size_t)blockIdx.x * 1024;   // block's 1024-float window

    // Per-lane global src (tid*4 floats = tid*16 B into the block window);
    // wave-uniform LDS dest (wid*256 floats = wid's 1 KB segment of each row).
    const float* vsrc = value  + (size_t)t0 * B_ + col0 + (size_t)tid * 4;
    const float* rsrc = reward + (size_t)t0 * B_ + col0 + (size_t)tid * 4;
    float* lwave = lds + wid * 256;

    #pragma unroll
    for (int k = 0; k <= L; ++k)               // value rows -> lds rows 0..L
        dma16(vsrc + (size_t)k * B_, lwave + k * 1024);
    #pragma unroll
    for (int k = 0; k < L; ++k)                // reward rows -> lds rows L+1..2L
        dma16(rsrc + (size_t)k * B_, lwave + (L + 1 + k) * 1024);

    // Wave-private staging: only this wave's vmcnt matters, no barrier.
    asm volatile("s_waitcnt vmcnt(0)" ::: "memory");

    const float* lcol = lds + (size_t)tid * 4; // this thread's column slice
    float4 vnext = *(const float4*)(lcol + L * 1024);
    float4 s = make_float4(0.f, 0.f, 0.f, 0.f);
    #pragma unroll
    for (int i = L - 1; i >= 0; --i) {
        float4 vi = *(const float4*)(lcol + i * 1024);
        float4 ri = *(const float4*)(lcol + (L + 1 + i) * 1024);
        s.x = (ri.x + GAMMA * vnext.x - vi.x) + COEF * s.x;
        s.y = (ri.y + GAMMA * vnext.y - vi.y) + COEF * s.y;
        s.z = (ri.z + GAMMA * vnext.z - vi.z) + COEF * s.z;
        s.w = (ri.w + GAMMA * vnext.w - vi.w) + COEF * s.w;
        vnext = vi;
    }
    *(float4*)(S + (size_t)chunk * B_ + col0 + (size_t)tid * 4) = s;
}

// ---------------- K2: in-place carry scan, one thread per scalar column ----
template<int C>
__global__ __launch_bounds__(256) void gae_carry(float* __restrict__ S)
{
    constexpr float CL = pow_coef(T_ / C);   // COEF^L
    const int col = blockIdx.x * 256 + threadIdx.x;   // 0..B-1

    float s[C];
    #pragma unroll
    for (int j = C - 1; j >= 0; --j)
        s[j] = S[(size_t)j * B_ + col];
    LOAD_FENCE();

    float run = 0.f;
    #pragma unroll
    for (int j = C - 1; j >= 0; --j) {
        S[(size_t)j * B_ + col] = run;                // carry entering chunk j
        run = s[j] + CL * run;
    }
}

// ---------------- K3: recompute local scan seeded with carry --------------
template<int L>
__global__ __launch_bounds__(256) void gae_out(
    const float* __restrict__ value,   // (T+1, B)  L3-hot from K1
    const float* __restrict__ reward,  // (T, B)    L3-hot from K1
    const float* __restrict__ S,       // (C, B)    now holds carries
    float* __restrict__ out)           // (T, B)    written once, nontemporal
{
    const int c4    = blockIdx.x * 256 + threadIdx.x;
    const int chunk = blockIdx.y;
    const size_t b  = (size_t)c4 * 4;
    const int t0    = chunk * L;

    float4 carry = *(const float4*)(S + (size_t)chunk * B_ + b);
    float4 v[L + 1];
    float4 r[L];
    #pragma unroll
    for (int i = L; i >= 0; --i)
        v[i] = *(const float4*)(value + (size_t)(t0 + i) * B_ + b);
    #pragma unroll
    for (int i = L - 1; i >= 0; --i)
        r[i] = *(const float4*)(reward + (size_t)(t0 + i) * B_ + b);
    LOAD_FENCE();

    float4 a = carry;
    #pragma unroll
    for (int i = L - 1; i >= 0; --i) {
        a.x = (r[i].x + GAMMA * v[i + 1].x - v[i].x) + COEF * a.x;
        a.y = (r[i].y + GAMMA * v[i + 1].y - v[i].y) + COEF * a.y;
        a.z = (r[i].z + GAMMA * v[i + 1].z - v[i].z) + COEF * a.z;
        a.w = (r[i].w + GAMMA * v[i + 1].w - v[i].w) + COEF * a.w;
        store_nt(out + (size_t)(t0 + i) * B_ + b, a);
    }
}

extern "C" void kernel_launch(void* const* d_in, const int* in_sizes, int n_in,
                              void* d_out, int out_size, void* d_ws, size_t ws_size,
                              hipStream_t stream) {
    const float* value  = (const float*)d_in[0];   // (T+1, B)
    const float* reward = (const float*)d_in[1];   // (T, B)
    float* out = (float*)d_out;
    float* S   = (float*)d_ws;                     // (C, B) = 8 MiB at L=8
                                                   // (ws >= 8 MiB confirmed: R4-R6
                                                   // ran the L=8 path, WRITE_SIZE=8192 KB)
    dim3 block(256);
    dim3 grid(B_ / 4 / 256, T_ / 8);               // (16, 128)
    dim3 gridC(B_ / 256);                          // 64 blocks, scalar columns

    gae_sum_dma<8> <<<grid,  block, 0, stream>>>(value, reward, S);
    gae_carry<T_/8><<<gridC, block, 0, stream>>>(S);
    gae_out<8>     <<<grid,  block, 0, stream>>>(value, reward, S, out);
}